// Round 1
// baseline (153.455 us; speedup 1.0000x reference)
//
#include <hip/hip_runtime.h>
#include <hip/hip_fp16.h>
#include <math.h>

#define N_NODES  100000
#define N_HID    128
#define N_ETYPES 10
#define N_EDGES  100000

#define EDGES_PER_HW 4  // fallback kernel only

typedef __attribute__((ext_vector_type(2))) _Float16 h2v;

#if defined(__has_builtin)
#if __has_builtin(__builtin_amdgcn_fdot2)
#define HAVE_FDOT2 1
#endif
#endif

__device__ __forceinline__ float dot2acc(h2v a, h2v b, float c) {
#ifdef HAVE_FDOT2
    return __builtin_amdgcn_fdot2(a, b, c, false);
#else
    return c + (float)a.x * (float)b.x + (float)a.y * (float)b.y;
#endif
}

// VALU-only cross-lane reduce: v_mov_b32_dpp row_ror:<N> + v_add_f32.
// Rotations 1,2,4,8 within each 16-lane row leave the full row sum in every lane.
// Replaces ds_swizzle-based __shfl_xor: zero LDS-pipe traffic.
template<int CTRL>
__device__ __forceinline__ float ror_add(float p) {
    int r = __builtin_amdgcn_update_dpp(0, __float_as_int(p), CTRL, 0xF, 0xF, true);
    return p + __int_as_float(r);
}

__device__ __forceinline__ float row16_sum(float p) {
    p = ror_add<0x121>(p);  // row_ror:1
    p = ror_add<0x122>(p);  // row_ror:2
    p = ror_add<0x124>(p);  // row_ror:4
    p = ror_add<0x128>(p);  // row_ror:8
    return p;
}

// ---------------- pass 1: h,W (fp32) -> fp16 in workspace ----------------
__global__ __launch_bounds__(256) void convert_kernel(
    const float* __restrict__ h, const float* __restrict__ W,
    __half* __restrict__ h16, __half* __restrict__ W16)
{
    const size_t i = ((size_t)blockIdx.x * 256 + threadIdx.x) * 8;
    const float4 f0 = *(const float4*)(h + i);
    const float4 f1 = *(const float4*)(h + i + 4);
    union { uint4 u; __half2 p[4]; } pk;
    pk.p[0] = __floats2half2_rn(f0.x, f0.y);
    pk.p[1] = __floats2half2_rn(f0.z, f0.w);
    pk.p[2] = __floats2half2_rn(f1.x, f1.y);
    pk.p[3] = __floats2half2_rn(f1.z, f1.w);
    *(uint4*)(h16 + i) = pk.u;

    if (blockIdx.x == 0 && threadIdx.x < (N_ETYPES * N_HID / 8)) {
        const size_t j = (size_t)threadIdx.x * 8;
        const float4 g0 = *(const float4*)(W + j);
        const float4 g1 = *(const float4*)(W + j + 4);
        union { uint4 u; __half2 p[4]; } pw;
        pw.p[0] = __floats2half2_rn(g0.x, g0.y);
        pw.p[1] = __floats2half2_rn(g0.z, g0.w);
        pw.p[2] = __floats2half2_rn(g1.x, g1.y);
        pw.p[3] = __floats2half2_rn(g1.z, g1.w);
        *(uint4*)(W16 + j) = pw.u;
    }
}

// ---------------- pass 2: gather + dot + sigmoid ----------------
// 16 lanes per edge: one dwordx4 per row (full 256B row per group per instr).
// Wave = 4 groups x 2 slots = 8 edges. No DS ops anywhere.
__device__ __forceinline__ float dot_row(uint4 a, uint4 b, const h2v uwp[4]) {
    union { uint4 u; h2v p[4]; } ua, ub;
    ua.u = a; ub.u = b;
    float p = dot2acc(ua.p[0], (h2v)(uwp[0] * ub.p[0]), 0.0f);
    p = dot2acc(ua.p[1], (h2v)(uwp[1] * ub.p[1]), p);
    p = dot2acc(ua.p[2], (h2v)(uwp[2] * ub.p[2]), p);
    p = dot2acc(ua.p[3], (h2v)(uwp[3] * ub.p[3]), p);
    return p;
}

__global__ __launch_bounds__(256) void distmult_score_f16_kernel(
    const __half* __restrict__ h16,
    const __half* __restrict__ W16,
    const int*    __restrict__ src,
    const int*    __restrict__ dst,
    const int*    __restrict__ rel,
    float*        __restrict__ out)
{
    const int t    = blockIdx.y;
    const int lane = threadIdx.x & 63;
    const int g    = lane >> 4;    // group (edge within slot)
    const int gl   = lane & 15;    // lane within group
    const int wid  = threadIdx.x >> 6;

    const int r = rel[t];
    union { uint4 u; h2v p[4]; } uw;
    uw.u = ((const uint4*)(W16 + (size_t)r * N_HID))[gl];

    const int base = t * N_EDGES;
    const int e0   = (blockIdx.x * 4 + wid) * 8;   // 8 edges per wave

    // per-lane broadcast index loads (all 16 lanes of a group read the same dword)
    const int* sp = src + base + e0 + g;
    const int* dp = dst + base + e0 + g;
    const int s0 = __builtin_nontemporal_load(sp);
    const int s1 = __builtin_nontemporal_load(sp + 4);
    const int d0 = __builtin_nontemporal_load(dp);
    const int d1 = __builtin_nontemporal_load(dp + 4);

    const unsigned col = (unsigned)gl << 3;        // 8 halfs (16B) per lane
    const uint4 A0 = *(const uint4*)(h16 + (((unsigned)s0 << 7) + col));
    const uint4 B0 = *(const uint4*)(h16 + (((unsigned)d0 << 7) + col));
    const uint4 A1 = *(const uint4*)(h16 + (((unsigned)s1 << 7) + col));
    const uint4 B1 = *(const uint4*)(h16 + (((unsigned)d1 << 7) + col));

    float p0 = dot_row(A0, B0, uw.p);
    float p1 = dot_row(A1, B1, uw.p);

    p0 = row16_sum(p0);
    p1 = row16_sum(p1);

    // slot s, group g -> edge e0 + 4*s + g; lanes gl==0/1 store slot 0/1
    if (gl < 2) {
        const float res = gl ? p1 : p0;
        const int e = e0 + g + (gl << 2);
        const float sig = 1.0f / (1.0f + __expf(-res));
        __builtin_nontemporal_store(sig, out + base + e);
    }
}

// ---------------- fallback (fp32 rows, no workspace) ----------------
__global__ __launch_bounds__(256) void distmult_score_f32_kernel(
    const float* __restrict__ h,
    const float* __restrict__ W,
    const int*   __restrict__ src,
    const int*   __restrict__ dst,
    const int*   __restrict__ rel,
    float*       __restrict__ out)
{
    const int t    = blockIdx.y;
    const int lane = threadIdx.x & 31;
    const int hw   = (blockIdx.x << 3) + (threadIdx.x >> 5);
    const int r = rel[t];
    const float4 w4 = ((const float4*)(W + (size_t)r * N_HID))[lane];
    const long base = (long)t * N_EDGES;
    const int  e0   = hw * EDGES_PER_HW;

    float res = 0.0f;
    #pragma unroll
    for (int k = 0; k < EDGES_PER_HW; ++k) {
        const int e = e0 + k;
        const int s = src[base + e];
        const int d = dst[base + e];
        const float4 a = ((const float4*)(h + (size_t)s * N_HID))[lane];
        const float4 b = ((const float4*)(h + (size_t)d * N_HID))[lane];
        float p = a.x * w4.x * b.x + a.y * w4.y * b.y
                + a.z * w4.z * b.z + a.w * w4.w * b.w;
        p += __shfl_xor(p, 16, 64);
        p += __shfl_xor(p, 8, 64);
        p += __shfl_xor(p, 4, 64);
        p += __shfl_xor(p, 2, 64);
        p += __shfl_xor(p, 1, 64);
        if (lane == k) res = p;
    }
    if (lane < EDGES_PER_HW) {
        out[base + e0 + lane] = 1.0f / (1.0f + __expf(-res));
    }
}

extern "C" void kernel_launch(void* const* d_in, const int* in_sizes, int n_in,
                              void* d_out, int out_size, void* d_ws, size_t ws_size,
                              hipStream_t stream) {
    const float* h   = (const float*)d_in[0];
    const float* W   = (const float*)d_in[1];
    const int*   src = (const int*)d_in[2];
    const int*   dst = (const int*)d_in[3];
    const int*   rel = (const int*)d_in[4];
    float*       out = (float*)d_out;

    const size_t h16_elems = (size_t)N_NODES * N_HID;                // 12.8M
    const size_t need = (h16_elems + N_ETYPES * N_HID) * sizeof(__half);

    dim3 grid(N_EDGES / 32, N_ETYPES);  // 3125 x 10, 32 edges/block
    dim3 block(256);

    if (ws_size >= need) {
        __half* h16 = (__half*)d_ws;
        __half* W16 = h16 + h16_elems;
        convert_kernel<<<(int)(h16_elems / (256 * 8)), 256, 0, stream>>>(h, W, h16, W16);
        distmult_score_f16_kernel<<<grid, block, 0, stream>>>(h16, W16, src, dst, rel, out);
    } else {
        distmult_score_f32_kernel<<<grid, block, 0, stream>>>(h, W, src, dst, rel, out);
    }
}